// Round 1
// baseline (195.432 us; speedup 1.0000x reference)
//
#include <hip/hip_runtime.h>

typedef __bf16 bf16x8 __attribute__((ext_vector_type(8)));
typedef float f32x4 __attribute__((ext_vector_type(4)));

#define AS1 __attribute__((address_space(1)))
#define AS3 __attribute__((address_space(3)))

static __device__ __forceinline__ unsigned int f2bf_rne(float f) {
  union { float f; unsigned int u; } v; v.f = f;
  return (v.u + 0x7FFFu + ((v.u >> 16) & 1u)) >> 16;
}

// ---------------- zero the output (it is poisoned 0xAA before timing) -------
__global__ void k_zero(float4* __restrict__ out) {
  out[blockIdx.x * 256 + threadIdx.x] = make_float4(0.f, 0.f, 0.f, 0.f);
}

// ---- W[f,d,e] -> bf16, tiled [kt][f][kl 0..127] (32KB tiles), XOR-swizzled --
// element (f,k): kt=k>>7, kl=k&127; byte = kt*32768 + f*256 + ((kl*2)^((f&7)<<4))
__global__ void k_wtile(const float* __restrict__ W, char* __restrict__ wt) {
  long i = (long)(blockIdx.x * 256 + threadIdx.x) * 4;   // 2M elements, 4/thread
  int f = (int)(i >> 14);
  int k = (int)(i & 16383);
  float4 w4 = *(const float4*)(W + i);
  int kt = k >> 7, kl = k & 127;
  unsigned int lo = f2bf_rne(w4.x) | (f2bf_rne(w4.y) << 16);
  unsigned int hi = f2bf_rne(w4.z) | (f2bf_rne(w4.w) << 16);
  int byo = f * 256 + ((kl * 2) ^ ((f & 7) << 4));
  unsigned int* dst = (unsigned int*)(wt + (long)kt * 32768 + byo);
  dst[0] = lo; dst[1] = hi;
}

// ---- decayed prefix scan, chunk-parallel with 128-token lookback -----------
// s[b,0]=0; s[b,t] = (s[b,t-1] + x[b,t-1]) / 1.2. Stored TRANSPOSED:
// st[e*8192 + (b*2048+t)]
__global__ void k_scan(const float* __restrict__ x, float* __restrict__ st) {
  int tid = blockIdx.x * 256 + threadIdx.x;   // 8192 threads
  int e  = tid & 127;
  int bc = tid >> 7;          // 0..63
  int b  = bc >> 4;
  int ch = bc & 15;
  int t0 = ch * 128;
  const float* xb = x + (long)b * 2048 * 128 + e;
  float* sb = st + (long)e * 8192 + b * 2048;
  const float inv = 1.0f / 1.2f;
  float c = 0.f;
  int ts = t0 - 128; if (ts < 0) ts = 0;
  for (int t = ts; t < t0; ++t) c = (c + xb[(long)t * 128]) * inv;
  for (int t = t0; t < t0 + 128; ++t) { sb[t] = c; c = (c + xb[(long)t * 128]) * inv; }
}

// ---------------- main: out[token,f] += sum_k (x[tok,d]*s[tok,e]) * W[f,k] --
// grid 256 = 64 token-tiles (BM=128) x K-split 4 (kq = bid&3 -> XCD pairing).
// 8 waves: wave = (ng = f-half, p = K-phase). Wave computes [128 tok x 64 f]
// partial over its phase; phases reduced in LDS at the end, then atomicAdd.
__global__ __launch_bounds__(512, 2) void k_main(
    const float* __restrict__ x, const float* __restrict__ st,
    const char* __restrict__ wt, float* __restrict__ out) {
  __shared__ __attribute__((aligned(128))) char lds[2 * 32768 + 128 * 33 * 4];
  float* x_lds = (float*)(lds + 65536);

  const int tid  = threadIdx.x;
  const int bid  = blockIdx.x;
  const int kq   = bid & 3;          // K-quarter (4096 k each)
  const int tt   = bid >> 2;         // token tile
  const int wv   = tid >> 6;
  const int lane = tid & 63;
  const int p    = wv & 3;           // K-phase within each 128-k tile
  const int ng   = wv >> 2;          // f half
  const int r    = lane & 15;
  const int kg   = lane >> 4;
  const int tokenBase = tt * 128;

  // stage x tile [128 tokens][pad-33, 32 d-values] (d = kq*32 + it)
  {
    int row = tid >> 2;
    int dd0 = (tid & 3) * 8;
    const float* src = x + (long)(tokenBase + row) * 128 + kq * 32 + dd0;
    #pragma unroll
    for (int q = 0; q < 8; ++q) x_lds[row * 33 + dd0 + q] = src[q];
  }

  // s values: phase-pinned -> each lane needs the SAME 8 e's for all K-steps.
  // e = p*32 + kg*8 + j. Pack as bf16 pairs: 32 VGPRs.
  unsigned int sreg[8][4];
  {
    const float* stb = st + tokenBase + (long)(p * 32 + kg * 8) * 8192;
    #pragma unroll
    for (int mr = 0; mr < 8; ++mr) {
      #pragma unroll
      for (int jj = 0; jj < 4; ++jj) {
        float lo = stb[(long)(jj * 2    ) * 8192 + mr * 16 + r];
        float hi = stb[(long)(jj * 2 + 1) * 8192 + mr * 16 + r];
        sreg[mr][jj] = f2bf_rne(lo) | (f2bf_rne(hi) << 16);
      }
    }
  }

  const char* wtq = wt + (long)kq * 32 * 32768;

  // prologue: stage tile 0 into buf 0 (linear dest = lane*16 per wave-chunk)
  {
    #pragma unroll
    for (int q = 0; q < 4; ++q) {
      int chunk = wv * 4 + q;
      const char* gs = wtq + chunk * 1024 + lane * 16;
      __builtin_amdgcn_global_load_lds((const AS1 unsigned int*)gs,
          (AS3 unsigned int*)(lds + chunk * 1024 + lane * 16), 16, 0, 0);
    }
  }
  __syncthreads();   // full drain: x_lds writes + tile0 ready for everyone

  f32x4 acc[8][4];
  #pragma unroll
  for (int mr = 0; mr < 8; ++mr)
    #pragma unroll
    for (int n = 0; n < 4; ++n)
      acc[mr][n] = (f32x4){0.f, 0.f, 0.f, 0.f};

  const int boff = (p * 64 + kg * 16) ^ ((r & 7) << 4);  // swizzled k-offset

  for (int it = 0; it < 32; ++it) {
    if (it + 1 < 32) {
      // issue next tile into the other buffer, then wait only current tile
      int nbuf = (it + 1) & 1;
      #pragma unroll
      for (int q = 0; q < 4; ++q) {
        int chunk = wv * 4 + q;
        const char* gs = wtq + (long)(it + 1) * 32768 + chunk * 1024 + lane * 16;
        __builtin_amdgcn_global_load_lds((const AS1 unsigned int*)gs,
            (AS3 unsigned int*)(lds + nbuf * 32768 + chunk * 1024 + lane * 16),
            16, 0, 0);
      }
      __asm__ __volatile__("s_waitcnt vmcnt(4)" ::: "memory");
    } else {
      __asm__ __volatile__("s_waitcnt vmcnt(0)" ::: "memory");
    }
    __asm__ __volatile__("s_barrier" ::: "memory");

    const char* wbuf = lds + (it & 1) * 32768;

    // generate A fragments: A[token, k] = x[token, d] * s[token, e]
    bf16x8 a[8];
    #pragma unroll
    for (int mr = 0; mr < 8; ++mr) {
      float xv = x_lds[(mr * 16 + r) * 33 + it];   // d uniform per tile
      #pragma unroll
      for (int jj = 0; jj < 4; ++jj) {
        unsigned int u = sreg[mr][jj];
        float slo = __uint_as_float(u << 16);
        float shi = __uint_as_float(u & 0xFFFF0000u);
        a[mr][jj * 2]     = (__bf16)(xv * slo);
        a[mr][jj * 2 + 1] = (__bf16)(xv * shi);
      }
    }
    // B fragments: lane = col f, 8 contiguous k; 4 frags reused over 8 M-reps
    #pragma unroll
    for (int n = 0; n < 4; ++n) {
      bf16x8 b = *(const bf16x8*)(wbuf + (ng * 64 + n * 16 + r) * 256 + boff);
      #pragma unroll
      for (int mr = 0; mr < 8; ++mr)
        acc[mr][n] = __builtin_amdgcn_mfma_f32_16x16x32_bf16(a[mr], b, acc[mr][n], 0, 0, 0);
    }
    __asm__ __volatile__("s_barrier" ::: "memory");
  }

  // epilogue: sum the 4 phase-waves' partials in LDS, then atomicAdd to out
  __syncthreads();
  float* red = (float*)lds;
  #pragma unroll
  for (int j = 0; j < 32; ++j) red[tid + j * 512] = 0.f;
  __syncthreads();
  #pragma unroll
  for (int mr = 0; mr < 8; ++mr)
    #pragma unroll
    for (int n = 0; n < 4; ++n)
      #pragma unroll
      for (int q = 0; q < 4; ++q)
        atomicAdd(&red[(mr * 16 + kg * 4 + q) * 128 + (ng * 64 + n * 16 + r)],
                  acc[mr][n][q]);   // C/D: col=lane&15, row=(lane>>4)*4+reg
  __syncthreads();
  float* outp = out + (long)tokenBase * 128;
  #pragma unroll
  for (int j = 0; j < 32; ++j) {
    int idx = tid + j * 512;
    atomicAdd(&outp[idx], red[idx]);
  }
}

extern "C" void kernel_launch(void* const* d_in, const int* in_sizes, int n_in,
                              void* d_out, int out_size, void* d_ws, size_t ws_size,
                              hipStream_t stream) {
  const float* x = (const float*)d_in[0];        // [4,2048,128] f32
  const float* W = (const float*)d_in[1];        // [128,128,128] f32
  float* out = (float*)d_out;                    // [4,2048,128] f32
  float* st  = (float*)d_ws;                     // 4 MB: s transposed [e][token]
  char*  wt  = (char*)d_ws + (4 << 20);          // 4 MB: W bf16 tiled+swizzled

  k_zero <<<dim3(1024), dim3(256), 0, stream>>>((float4*)out);
  k_wtile<<<dim3(2048), dim3(256), 0, stream>>>(W, wt);
  k_scan <<<dim3(32),   dim3(256), 0, stream>>>(x, st);
  k_main <<<dim3(256),  dim3(512), 0, stream>>>(x, st, wt, out);
}

// Round 2
// 100.186 us; speedup vs baseline: 1.9507x; 1.9507x over previous
//
#include <hip/hip_runtime.h>

typedef __bf16 bf16x8 __attribute__((ext_vector_type(8)));
typedef float f32x4 __attribute__((ext_vector_type(4)));

#define AS1 __attribute__((address_space(1)))
#define AS3 __attribute__((address_space(3)))

static __device__ __forceinline__ unsigned int f2bf_rne(float f) {
  union { float f; unsigned int u; } v; v.f = f;
  return (v.u + 0x7FFFu + ((v.u >> 16) & 1u)) >> 16;
}

// ---------------- zero the output (poisoned 0xAA before timing) -------------
__global__ void k_zero(float4* __restrict__ out) {
  out[blockIdx.x * 256 + threadIdx.x] = make_float4(0.f, 0.f, 0.f, 0.f);
}

// ---- W[f,d,e] -> bf16, per-d 32KB tiles [d][f][128e], XOR-swizzled ---------
// element (f,k): d=k>>7, e=k&127; byte = d*32768 + f*256 + ((e*2)^((f&7)<<4))
__global__ void k_wtile(const float* __restrict__ W, char* __restrict__ wt) {
  long i = (long)(blockIdx.x * 256 + threadIdx.x) * 4;   // 2M elements, 4/thread
  int f = (int)(i >> 14);
  int k = (int)(i & 16383);
  float4 w4 = *(const float4*)(W + i);
  int kt = k >> 7, kl = k & 127;
  unsigned int lo = f2bf_rne(w4.x) | (f2bf_rne(w4.y) << 16);
  unsigned int hi = f2bf_rne(w4.z) | (f2bf_rne(w4.w) << 16);
  int byo = f * 256 + ((kl * 2) ^ ((f & 7) << 4));
  unsigned int* dst = (unsigned int*)(wt + (long)kt * 32768 + byo);
  dst[0] = lo; dst[1] = hi;
}

// ---- decayed prefix scan, 64-token chunks with 64-token lookback -----------
// (1.2^-64 ~ 8.5e-6 relative: far below bf16 noise). Stored TRANSPOSED:
// st[e*8192 + (b*2048+t)]
__global__ void k_scan(const float* __restrict__ x, float* __restrict__ st) {
  int tid = blockIdx.x * 256 + threadIdx.x;   // 16384 threads
  int e  = tid & 127;
  int bc = tid >> 7;          // 0..127
  int b  = bc >> 5;
  int ch = bc & 31;
  int t0 = ch * 64;
  const float* xb = x + (long)b * 2048 * 128 + e;
  float* sb = st + (long)e * 8192 + b * 2048;
  const float inv = 1.0f / 1.2f;
  float c = 0.f;
  int ts = t0 - 64; if (ts < 0) ts = 0;
  for (int t = ts; t < t0; ++t) c = (c + xb[(long)t * 128]) * inv;
  for (int t = t0; t < t0 + 64; ++t) { sb[t] = c; c = (c + xb[(long)t * 128]) * inv; }
}

// ---------------- main: out[token,f] += sum_k (x[tok,d]*s[tok,e]) * W[f,k] --
// grid 1024 = 128 token-tiles (BM=64) x K-split 8 (kq = bid&7 -> one W slice
// per XCD, L2-resident). 4 waves = 4 e-phases (32 e's each, full N=128).
// 2 blocks/CU (LDS ~70KB, ~190 VGPR) so stalls overlap across blocks.
__global__ __launch_bounds__(256, 2) void k_main(
    const float* __restrict__ x, const float* __restrict__ st,
    const char* __restrict__ wt, float* __restrict__ out) {
  __shared__ __attribute__((aligned(128))) char lds[65536 + 64 * 20 * 4];
  float* x_lds = (float*)(lds + 65536);

  const int tid  = threadIdx.x;
  const int bid  = blockIdx.x;
  const int kq   = bid & 7;          // K-eighth: d in [kq*16, kq*16+16)
  const int tt   = bid >> 3;         // token tile (0..127)
  const int wv   = tid >> 6;         // e-phase p (0..3)
  const int lane = tid & 63;
  const int r    = lane & 15;
  const int kg   = lane >> 4;
  const int tokenBase = tt * 64;

  // stage x tile [64 tokens][pad-20, 16 d-values] (d = kq*16 + it)
  {
    int row = tid >> 2, c0 = (tid & 3) * 4;
    const float* src = x + (long)(tokenBase + row) * 128 + kq * 16 + c0;
    *(float4*)&x_lds[row * 20 + c0] = *(const float4*)src;
  }

  // s values: wave owns e = wv*32 + kg*8 + {0..7} for ALL tiles. 16 VGPRs.
  unsigned int sreg[4][4];
  {
    const float* stb = st + tokenBase + (long)(wv * 32 + kg * 8) * 8192;
    #pragma unroll
    for (int mr = 0; mr < 4; ++mr)
      #pragma unroll
      for (int jj = 0; jj < 4; ++jj) {
        const float* qp = stb + (long)(2 * jj) * 8192 + mr * 16 + r;
        sreg[mr][jj] = f2bf_rne(qp[0]) | (f2bf_rne(qp[8192]) << 16);
      }
  }

  const char* wtq = wt + (long)(kq * 16) * 32768;

  // prologue: stage tile 0 into buf 0 (32KB, 8KB per wave)
  #pragma unroll
  for (int q = 0; q < 8; ++q) {
    int off = (wv * 8 + q) * 1024 + lane * 16;
    __builtin_amdgcn_global_load_lds((const AS1 unsigned int*)(wtq + off),
        (AS3 unsigned int*)(lds + off), 16, 0, 0);
  }
  __syncthreads();

  f32x4 acc[4][8];
  #pragma unroll
  for (int mr = 0; mr < 4; ++mr)
    #pragma unroll
    for (int n = 0; n < 8; ++n) acc[mr][n] = (f32x4){0.f, 0.f, 0.f, 0.f};

  const int boff = (wv * 64 + kg * 16) ^ ((r & 7) << 4);  // swizzled e-offset

  for (int it = 0; it < 16; ++it) {
    if (it < 15) {   // prefetch next tile into other buffer (before compute)
      const char* gs = wtq + (long)(it + 1) * 32768;
      char* ld = lds + ((it + 1) & 1) * 32768;
      #pragma unroll
      for (int q = 0; q < 8; ++q) {
        int off = (wv * 8 + q) * 1024 + lane * 16;
        __builtin_amdgcn_global_load_lds((const AS1 unsigned int*)(gs + off),
            (AS3 unsigned int*)(ld + off), 16, 0, 0);
      }
    }
    const char* wbuf = lds + (it & 1) * 32768;

    // A fragments: A[token, k] = x[token, d] * s[token, e]; d uniform per tile
    bf16x8 a[4];
    #pragma unroll
    for (int mr = 0; mr < 4; ++mr) {
      float xv = x_lds[(mr * 16 + r) * 20 + it];
      #pragma unroll
      for (int jj = 0; jj < 4; ++jj) {
        unsigned int u = sreg[mr][jj];
        float slo = __uint_as_float(u << 16);
        float shi = __uint_as_float(u & 0xFFFF0000u);
        a[mr][jj * 2]     = (__bf16)(xv * slo);
        a[mr][jj * 2 + 1] = (__bf16)(xv * shi);
      }
    }
    // B fragments: col f = n*16+r, 8 contiguous e; reused over 4 M-reps
    #pragma unroll
    for (int n = 0; n < 8; ++n) {
      bf16x8 b = *(const bf16x8*)(wbuf + (n * 16 + r) * 256 + boff);
      #pragma unroll
      for (int mr = 0; mr < 4; ++mr)
        acc[mr][n] = __builtin_amdgcn_mfma_f32_16x16x32_bf16(a[mr], b, acc[mr][n], 0, 0, 0);
    }
    __syncthreads();
  }

  // epilogue: reduce the 4 e-phase waves in LDS (buf0 is free), then atomicAdd
  float* red = (float*)lds;   // [64 tok][128 f] f32 = 32KB
  #pragma unroll
  for (int w2 = 0; w2 < 4; ++w2) {
    if (wv == w2) {
      #pragma unroll
      for (int mr = 0; mr < 4; ++mr)
        #pragma unroll
        for (int n = 0; n < 8; ++n)
          #pragma unroll
          for (int q2 = 0; q2 < 4; ++q2) {
            int idx = (mr * 16 + kg * 4 + q2) * 128 + n * 16 + r;
            if (w2 == 0) red[idx] = acc[mr][n][q2];
            else         red[idx] += acc[mr][n][q2];
          }
    }
    __syncthreads();
  }
  float* outp = out + (long)tokenBase * 128;
  #pragma unroll
  for (int j = 0; j < 32; ++j) {
    int idx = tid + j * 256;
    atomicAdd(&outp[idx], red[idx]);
  }
}

extern "C" void kernel_launch(void* const* d_in, const int* in_sizes, int n_in,
                              void* d_out, int out_size, void* d_ws, size_t ws_size,
                              hipStream_t stream) {
  const float* x = (const float*)d_in[0];        // [4,2048,128] f32
  const float* W = (const float*)d_in[1];        // [128,128,128] f32
  float* out = (float*)d_out;                    // [4,2048,128] f32
  float* st  = (float*)d_ws;                     // 4 MB: s transposed [e][token]
  char*  wt  = (char*)d_ws + (4 << 20);          // 4 MB: W bf16 tiled+swizzled

  k_zero <<<dim3(1024), dim3(256), 0, stream>>>((float4*)out);
  k_wtile<<<dim3(2048), dim3(256), 0, stream>>>(W, wt);
  k_scan <<<dim3(64),   dim3(256), 0, stream>>>(x, st);
  k_main <<<dim3(1024), dim3(256), 0, stream>>>(x, st, wt, out);
}

// Round 3
// 86.310 us; speedup vs baseline: 2.2643x; 1.1608x over previous
//
#include <hip/hip_runtime.h>

typedef __bf16 bf16x8 __attribute__((ext_vector_type(8)));
typedef float f32x4 __attribute__((ext_vector_type(4)));

static __device__ __forceinline__ unsigned int f2bf_rne(float f) {
  union { float f; unsigned int u; } v; v.f = f;
  return (v.u + 0x7FFFu + ((v.u >> 16) & 1u)) >> 16;
}

// ---------------- zero the output (poisoned 0xAA before timing) -------------
__global__ void k_zero(float4* __restrict__ out) {
  out[blockIdx.x * 256 + threadIdx.x] = make_float4(0.f, 0.f, 0.f, 0.f);
}

// ---- W[f,d,e] -> bf16, layout [d][wv][f][32e]: per-(d,wave) 8KB contiguous -
// element (f,k): d=k>>7, e=k&127:
// byte = d*32768 + (e>>5)*8192 + f*64 + ((e>>3)&3)*16 + (e&7)*2
__global__ void k_wtile(const float* __restrict__ W, char* __restrict__ wt) {
  long i = (long)(blockIdx.x * 256 + threadIdx.x) * 4;   // 2M elements, 4/thread
  int f = (int)(i >> 14);
  int k = (int)(i & 16383);
  float4 w4 = *(const float4*)(W + i);
  int d = k >> 7, e = k & 127;
  unsigned int lo = f2bf_rne(w4.x) | (f2bf_rne(w4.y) << 16);
  unsigned int hi = f2bf_rne(w4.z) | (f2bf_rne(w4.w) << 16);
  long byo = (long)d * 32768 + (e >> 5) * 8192 + f * 64 + ((e >> 3) & 3) * 16 + (e & 7) * 2;
  unsigned int* dst = (unsigned int*)(wt + byo);
  dst[0] = lo; dst[1] = hi;
}

// ---- decayed prefix scan, 64-token chunks with 64-token lookback -----------
// (1.2^-64 ~ 8.5e-6 relative). Stored TRANSPOSED: st[e*8192 + (b*2048+t)]
__global__ void k_scan(const float* __restrict__ x, float* __restrict__ st) {
  int tid = blockIdx.x * 256 + threadIdx.x;   // 16384 threads
  int e  = tid & 127;
  int bc = tid >> 7;          // 0..127
  int b  = bc >> 5;
  int ch = bc & 31;
  int t0 = ch * 64;
  const float* xb = x + (long)b * 2048 * 128 + e;
  float* sb = st + (long)e * 8192 + b * 2048;
  const float inv = 1.0f / 1.2f;
  float c = 0.f;
  int ts = t0 - 64; if (ts < 0) ts = 0;
  for (int t = ts; t < t0; ++t) c = (c + xb[(long)t * 128]) * inv;
  for (int t = t0; t < t0 + 64; ++t) { sb[t] = c; c = (c + xb[(long)t * 128]) * inv; }
}

// ---------------- main: out[token,f] += sum_k (x[tok,d]*s[tok,e]) * W[f,k] --
// grid 512 = 128 token-tiles (BM=64) x K-split 4. kq=bid&3 -> XCD bid&7 sees
// exactly one 1MB W slice (L2-resident). 4 waves = 4 e-phases; W goes straight
// global->VGPR (contiguous 1KB loads), double-buffered, NO barriers in K-loop.
__global__ __launch_bounds__(256, 2) void k_main(
    const float* __restrict__ x, const float* __restrict__ st,
    const char* __restrict__ wt, float* __restrict__ out) {
  __shared__ __attribute__((aligned(128))) float lds_red[64 * 128];  // 32KB
  float* x_lds = lds_red;   // first 9KB double as x tile [64][pad36]

  const int tid  = threadIdx.x;
  const int bid  = blockIdx.x;
  const int kq   = bid & 3;          // K-quarter: d in [kq*32, kq*32+32)
  const int tt   = bid >> 2;         // token tile (0..127)
  const int wv   = tid >> 6;         // e-phase (0..3)
  const int lane = tid & 63;
  const int r    = lane & 15;
  const int kg   = lane >> 4;
  const int tokenBase = tt * 64;

  // stage x tile [64 tokens][pad36] (cols = d = kq*32 + it, it 0..31)
  {
    int row = tid >> 2, c0 = (tid & 3) * 8;
    const float* src = x + (long)(tokenBase + row) * 128 + kq * 32 + c0;
    *(float4*)&x_lds[row * 36 + c0]     = *(const float4*)src;
    *(float4*)&x_lds[row * 36 + c0 + 4] = *(const float4*)(src + 4);
  }

  // s values: wave owns e = wv*32 + kg*8 + {0..7} for ALL d. 16 VGPRs.
  unsigned int sreg[4][4];
  {
    const float* stb = st + tokenBase + (long)(wv * 32 + kg * 8) * 8192;
    #pragma unroll
    for (int mr = 0; mr < 4; ++mr)
      #pragma unroll
      for (int jj = 0; jj < 4; ++jj) {
        const float* qp = stb + (long)(2 * jj) * 8192 + mr * 16 + r;
        sreg[mr][jj] = f2bf_rne(qp[0]) | (f2bf_rne(qp[8192]) << 16);
      }
  }
  __syncthreads();   // x_lds ready (only barrier before epilogue)

  f32x4 acc[4][8];
  #pragma unroll
  for (int mr = 0; mr < 4; ++mr)
    #pragma unroll
    for (int n = 0; n < 8; ++n) acc[mr][n] = (f32x4){0.f, 0.f, 0.f, 0.f};

  const int loff = r * 64 + kg * 16;                       // lane's byte slot
  const char* wtq = wt + (long)(kq * 32 * 4 + wv) * 8192;  // this wave's slice

#define AGEN(AOUT, IT)                                                    \
  {                                                                       \
    _Pragma("unroll")                                                     \
    for (int mr = 0; mr < 4; ++mr) {                                      \
      float xv = x_lds[(mr * 16 + r) * 36 + (IT)];                        \
      _Pragma("unroll")                                                   \
      for (int jj = 0; jj < 4; ++jj) {                                    \
        unsigned int u = sreg[mr][jj];                                    \
        float slo = __uint_as_float(u << 16);                             \
        float shi = __uint_as_float(u & 0xFFFF0000u);                     \
        AOUT[mr][jj * 2]     = (__bf16)(xv * slo);                        \
        AOUT[mr][jj * 2 + 1] = (__bf16)(xv * shi);                        \
      }                                                                   \
    }                                                                     \
  }
#define MFMAS(A, B)                                                       \
  {                                                                       \
    _Pragma("unroll")                                                     \
    for (int n = 0; n < 8; ++n)                                           \
      _Pragma("unroll")                                                   \
      for (int mr = 0; mr < 4; ++mr)                                      \
        acc[mr][n] = __builtin_amdgcn_mfma_f32_16x16x32_bf16(             \
            A[mr], B[n], acc[mr][n], 0, 0, 0);                            \
  }

  bf16x8 b0[8], b1[8], a[4];
  #pragma unroll
  for (int n = 0; n < 8; ++n) b0[n] = *(const bf16x8*)(wtq + n * 1024 + loff);

  #pragma unroll 1
  for (int it = 0; it < 32; it += 2) {
    {  // half A: prefetch it+1 -> b1, compute with b0
      const char* wn = wtq + (long)(it + 1) * 32768;
      #pragma unroll
      for (int n = 0; n < 8; ++n) b1[n] = *(const bf16x8*)(wn + n * 1024 + loff);
      AGEN(a, it);
      MFMAS(a, b0);
    }
    {  // half B: prefetch it+2 -> b0, compute with b1
      if (it + 2 < 32) {
        const char* wn = wtq + (long)(it + 2) * 32768;
        #pragma unroll
        for (int n = 0; n < 8; ++n) b0[n] = *(const bf16x8*)(wn + n * 1024 + loff);
      }
      AGEN(a, it + 1);
      MFMAS(a, b1);
    }
  }
#undef AGEN
#undef MFMAS

  // epilogue: reduce 4 e-phase waves in LDS, then atomicAdd to out
  __syncthreads();   // all x_lds reads done; lds_red reuse safe
  #pragma unroll
  for (int w2 = 0; w2 < 4; ++w2) {
    if (wv == w2) {
      #pragma unroll
      for (int mr = 0; mr < 4; ++mr)
        #pragma unroll
        for (int n = 0; n < 8; ++n)
          #pragma unroll
          for (int q2 = 0; q2 < 4; ++q2) {
            int idx = (mr * 16 + kg * 4 + q2) * 128 + n * 16 + r;
            if (w2 == 0) lds_red[idx] = acc[mr][n][q2];
            else         lds_red[idx] += acc[mr][n][q2];
          }
    }
    __syncthreads();
  }
  float* outp = out + (long)tokenBase * 128;
  #pragma unroll
  for (int j = 0; j < 32; ++j) {
    int idx = tid + j * 256;
    atomicAdd(&outp[idx], lds_red[idx]);
  }
}

extern "C" void kernel_launch(void* const* d_in, const int* in_sizes, int n_in,
                              void* d_out, int out_size, void* d_ws, size_t ws_size,
                              hipStream_t stream) {
  const float* x = (const float*)d_in[0];        // [4,2048,128] f32
  const float* W = (const float*)d_in[1];        // [128,128,128] f32
  float* out = (float*)d_out;                    // [4,2048,128] f32
  float* st  = (float*)d_ws;                     // 4 MB: s transposed [e][token]
  char*  wt  = (char*)d_ws + (4 << 20);          // 4 MB: W bf16 retiled

  k_zero <<<dim3(1024), dim3(256), 0, stream>>>((float4*)out);
  k_wtile<<<dim3(2048), dim3(256), 0, stream>>>(W, wt);
  k_scan <<<dim3(64),   dim3(256), 0, stream>>>(x, st);
  k_main <<<dim3(512),  dim3(256), 0, stream>>>(x, st, wt, out);
}